// Round 1
// baseline (817.988 us; speedup 1.0000x reference)
//
#include <hip/hip_runtime.h>
#include <hip/hip_bf16.h>
#include <cstdint>

// Problem constants (fixed by the reference)
constexpr int  KDIM  = 4096;    // D_IN
constexpr int  NDIM  = 4096;    // D_OUT
constexpr long MDIM  = 16384;   // B*S = 4*4096
constexpr int  RANK_ = 16;
constexpr float SCALE_ = 2.0f;  // alpha/rank

using bf16x8 = __attribute__((ext_vector_type(8))) short;  // 8 bf16 = 4 VGPRs
using f32x4  = __attribute__((ext_vector_type(4))) float;  // MFMA accumulator

// async global->LDS, 16B per lane. LDS dest must be wave-uniform; HW adds lane*16.
__device__ __forceinline__ void gload_lds16(const void* g, void* l) {
  __builtin_amdgcn_global_load_lds(
      (const __attribute__((address_space(1))) void*)g,
      (__attribute__((address_space(3))) void*)l, 16, 0, 0);
}

// fp32 -> bf16 RNE bit-twiddle
__device__ __forceinline__ unsigned short f2bf(float f) {
  union { float f; unsigned u; } v; v.f = f;
  unsigned r = v.u + 0x7FFFu + ((v.u >> 16) & 1u);
  return (unsigned short)(r >> 16);
}

// ---------------------------------------------------------------------------
// Kernel 1: W' = bf16( W + SCALE * lora_B @ lora_A )   [NDIM][KDIM]
// ---------------------------------------------------------------------------
__global__ __launch_bounds__(256) void prep_w_kernel(
    const float* __restrict__ W, const float* __restrict__ lA,
    const float* __restrict__ lB, unsigned short* __restrict__ Wp) {
  const long total8 = (long)NDIM * KDIM / 8;
  for (long t = blockIdx.x * (long)blockDim.x + threadIdx.x; t < total8;
       t += (long)gridDim.x * blockDim.x) {
    const int o  = (int)(t / (KDIM / 8));
    const int d8 = (int)(t % (KDIM / 8)) * 8;
    const float4* w4 = reinterpret_cast<const float4*>(W + (size_t)o * KDIM + d8);
    float4 w0 = w4[0], w1 = w4[1];
    float acc[8] = {w0.x, w0.y, w0.z, w0.w, w1.x, w1.y, w1.z, w1.w};
#pragma unroll
    for (int r = 0; r < RANK_; ++r) {
      const float br = SCALE_ * lB[o * RANK_ + r];
      const float4* a4 = reinterpret_cast<const float4*>(lA + (size_t)r * KDIM + d8);
      float4 a0 = a4[0], a1 = a4[1];
      acc[0] += br * a0.x; acc[1] += br * a0.y; acc[2] += br * a0.z; acc[3] += br * a0.w;
      acc[4] += br * a1.x; acc[5] += br * a1.y; acc[6] += br * a1.z; acc[7] += br * a1.w;
    }
    uint4 o4;
    o4.x = (unsigned)f2bf(acc[0]) | ((unsigned)f2bf(acc[1]) << 16);
    o4.y = (unsigned)f2bf(acc[2]) | ((unsigned)f2bf(acc[3]) << 16);
    o4.z = (unsigned)f2bf(acc[4]) | ((unsigned)f2bf(acc[5]) << 16);
    o4.w = (unsigned)f2bf(acc[6]) | ((unsigned)f2bf(acc[7]) << 16);
    *reinterpret_cast<uint4*>(Wp + t * 8) = o4;
  }
}

// ---------------------------------------------------------------------------
// Kernel 2: xb = bf16(x)   [MDIM][KDIM]
// ---------------------------------------------------------------------------
__global__ __launch_bounds__(256) void conv_x_kernel(
    const float* __restrict__ x, unsigned short* __restrict__ xb) {
  const long total8 = MDIM * KDIM / 8;
  for (long t = blockIdx.x * (long)blockDim.x + threadIdx.x; t < total8;
       t += (long)gridDim.x * blockDim.x) {
    const float4* p = reinterpret_cast<const float4*>(x + t * 8);
    float4 a = p[0], b = p[1];
    uint4 o4;
    o4.x = (unsigned)f2bf(a.x) | ((unsigned)f2bf(a.y) << 16);
    o4.y = (unsigned)f2bf(a.z) | ((unsigned)f2bf(a.w) << 16);
    o4.z = (unsigned)f2bf(b.x) | ((unsigned)f2bf(b.y) << 16);
    o4.w = (unsigned)f2bf(b.z) | ((unsigned)f2bf(b.w) << 16);
    *reinterpret_cast<uint4*>(xb + t * 8) = o4;
  }
}

// ---------------------------------------------------------------------------
// Kernel 3: C[M][N] = A[M][K] @ Bm[N][K]^T + bias   (m97 structure, 128x128 tile)
//   4 waves in 2x2; each wave owns a 64x64 subtile = 4x4 fragments of 16x16.
//   BK=32 => one mfma_f32_16x16x32_bf16 per fragment pair per K-step.
// ---------------------------------------------------------------------------
__global__ __launch_bounds__(256) void gemm_bt_kernel(
    const unsigned short* __restrict__ A,   // [MDIM][KDIM] bf16 bits
    const unsigned short* __restrict__ Bm,  // [NDIM][KDIM] bf16 bits (W')
    const float* __restrict__ bias,         // [NDIM]
    float* __restrict__ C) {                // [MDIM][NDIM]
  constexpr int BK = 32;
  __shared__ __align__(16) unsigned short As[128][BK];  // 8 KiB
  __shared__ __align__(16) unsigned short Bs[128][BK];  // 8 KiB

  const int tid  = threadIdx.x;
  const int wave = tid >> 6;        // 0..3
  const int lane = tid & 63;
  const int wr = wave >> 1;         // wave row (0..1) -> 64 rows
  const int wc = wave & 1;          // wave col (0..1) -> 64 cols
  const int r16 = lane & 15;
  const int hi  = lane >> 4;        // 0..3: k-chunk of 8 for A/B frags

  const int brow = blockIdx.y * 128;
  const int bcol = blockIdx.x * 128;

  // staging: lane l covers LDS bytes [base + l*16); source row/col within tile:
  const int srow = lane >> 2;         // 0..15
  const int scol = (lane & 3) * 8;    // 0,8,16,24 (elements)

  const unsigned short* Abase = A  + (size_t)brow * KDIM;
  const unsigned short* Bbase = Bm + (size_t)bcol * KDIM;

  f32x4 acc[4][4];
#pragma unroll
  for (int mi = 0; mi < 4; ++mi)
#pragma unroll
    for (int ni = 0; ni < 4; ++ni) acc[mi][ni] = (f32x4){0.f, 0.f, 0.f, 0.f};

  for (int k0 = 0; k0 < KDIM; k0 += BK) {
    // stage A-tile and B-tile: per wave, 2 chunks of 16 rows each (1 KiB/chunk)
#pragma unroll
    for (int j = 0; j < 2; ++j) {
      const int row = j * 64 + wave * 16;  // wave-uniform LDS base row
      gload_lds16(Abase + (size_t)(row + srow) * KDIM + k0 + scol, &As[row][0]);
      gload_lds16(Bbase + (size_t)(row + srow) * KDIM + k0 + scol, &Bs[row][0]);
    }
    __syncthreads();  // compiler emits vmcnt(0) drain before barrier

    bf16x8 af[4], bfr[4];
#pragma unroll
    for (int mi = 0; mi < 4; ++mi)
      af[mi] = *reinterpret_cast<const bf16x8*>(&As[wr * 64 + mi * 16 + r16][hi * 8]);
#pragma unroll
    for (int ni = 0; ni < 4; ++ni)
      bfr[ni] = *reinterpret_cast<const bf16x8*>(&Bs[wc * 64 + ni * 16 + r16][hi * 8]);
#pragma unroll
    for (int mi = 0; mi < 4; ++mi)
#pragma unroll
      for (int ni = 0; ni < 4; ++ni)
        acc[mi][ni] = __builtin_amdgcn_mfma_f32_16x16x32_bf16(
            af[mi], bfr[ni], acc[mi][ni], 0, 0, 0);
    __syncthreads();
  }

  // epilogue: C/D layout (verified m89/m91): row=(lane>>4)*4+reg, col=lane&15
#pragma unroll
  for (int ni = 0; ni < 4; ++ni) {
    const int col = bcol + wc * 64 + ni * 16 + r16;
    const float bv = bias[col];
#pragma unroll
    for (int mi = 0; mi < 4; ++mi) {
      const int row0 = brow + wr * 64 + mi * 16 + hi * 4;
#pragma unroll
      for (int j = 0; j < 4; ++j)
        C[(size_t)(row0 + j) * NDIM + col] = acc[mi][ni][j] + bv;
    }
  }
}

// ---------------------------------------------------------------------------
extern "C" void kernel_launch(void* const* d_in, const int* in_sizes, int n_in,
                              void* d_out, int out_size, void* d_ws, size_t ws_size,
                              hipStream_t stream) {
  const float* x  = (const float*)d_in[0];   // [4,4096,4096]
  const float* W  = (const float*)d_in[1];   // [4096,4096]
  const float* b  = (const float*)d_in[2];   // [4096]
  const float* lA = (const float*)d_in[3];   // [16,4096]
  const float* lB = (const float*)d_in[4];   // [4096,16]
  float* out = (float*)d_out;                // [4,4096,4096] fp32

  // workspace layout: xb (134 MiB) | Wp (32 MiB)
  unsigned short* xb = (unsigned short*)d_ws;
  unsigned short* Wp = (unsigned short*)((char*)d_ws + (size_t)MDIM * KDIM * 2);

  conv_x_kernel<<<2048, 256, 0, stream>>>(x, xb);
  prep_w_kernel<<<2048, 256, 0, stream>>>(W, lA, lB, Wp);

  dim3 grid(NDIM / 128, (int)(MDIM / 128));  // 32 x 128 blocks
  gemm_bt_kernel<<<grid, 256, 0, stream>>>(xb, Wp, b, out);
}

// Round 2
// 641.995 us; speedup vs baseline: 1.2741x; 1.2741x over previous
//
#include <hip/hip_runtime.h>
#include <hip/hip_bf16.h>
#include <cstdint>

// Problem constants (fixed by the reference)
constexpr int  KDIM  = 4096;    // D_IN
constexpr int  NDIM  = 4096;    // D_OUT
constexpr long MDIM  = 16384;   // B*S
constexpr int  RANK_ = 16;
constexpr float SCALE_ = 2.0f;  // alpha/rank

constexpr int BK = 64;
constexpr int NT = KDIM / BK;   // 64 K-tiles

using bf16x8 = __attribute__((ext_vector_type(8))) short;
using f32x4  = __attribute__((ext_vector_type(4))) float;

__device__ __forceinline__ void gload_lds16(const void* g, void* l) {
  __builtin_amdgcn_global_load_lds(
      (const __attribute__((address_space(1))) void*)g,
      (__attribute__((address_space(3))) void*)l, 16, 0, 0);
}

__device__ __forceinline__ unsigned short f2bf(float f) {
  union { float f; unsigned u; } v; v.f = f;
  unsigned r = v.u + 0x7FFFu + ((v.u >> 16) & 1u);
  return (unsigned short)(r >> 16);
}

// ---------------------------------------------------------------------------
// Kernel 1: W' = bf16( W + SCALE * lora_B @ lora_A )   [NDIM][KDIM]
// ---------------------------------------------------------------------------
__global__ __launch_bounds__(256) void prep_w_kernel(
    const float* __restrict__ W, const float* __restrict__ lA,
    const float* __restrict__ lB, unsigned short* __restrict__ Wp) {
  const long total8 = (long)NDIM * KDIM / 8;
  for (long t = blockIdx.x * (long)blockDim.x + threadIdx.x; t < total8;
       t += (long)gridDim.x * blockDim.x) {
    const int o  = (int)(t / (KDIM / 8));
    const int d8 = (int)(t % (KDIM / 8)) * 8;
    const float4* w4 = reinterpret_cast<const float4*>(W + (size_t)o * KDIM + d8);
    float4 w0 = w4[0], w1 = w4[1];
    float acc[8] = {w0.x, w0.y, w0.z, w0.w, w1.x, w1.y, w1.z, w1.w};
#pragma unroll
    for (int r = 0; r < RANK_; ++r) {
      const float br = SCALE_ * lB[o * RANK_ + r];
      const float4* a4 = reinterpret_cast<const float4*>(lA + (size_t)r * KDIM + d8);
      float4 a0 = a4[0], a1 = a4[1];
      acc[0] += br * a0.x; acc[1] += br * a0.y; acc[2] += br * a0.z; acc[3] += br * a0.w;
      acc[4] += br * a1.x; acc[5] += br * a1.y; acc[6] += br * a1.z; acc[7] += br * a1.w;
    }
    uint4 o4;
    o4.x = (unsigned)f2bf(acc[0]) | ((unsigned)f2bf(acc[1]) << 16);
    o4.y = (unsigned)f2bf(acc[2]) | ((unsigned)f2bf(acc[3]) << 16);
    o4.z = (unsigned)f2bf(acc[4]) | ((unsigned)f2bf(acc[5]) << 16);
    o4.w = (unsigned)f2bf(acc[6]) | ((unsigned)f2bf(acc[7]) << 16);
    *reinterpret_cast<uint4*>(Wp + t * 8) = o4;
  }
}

// ---------------------------------------------------------------------------
// Kernel 2: xb = bf16(x)   [MDIM][KDIM]
// ---------------------------------------------------------------------------
__global__ __launch_bounds__(256) void conv_x_kernel(
    const float* __restrict__ x, unsigned short* __restrict__ xb) {
  const long total8 = MDIM * KDIM / 8;
  for (long t = blockIdx.x * (long)blockDim.x + threadIdx.x; t < total8;
       t += (long)gridDim.x * blockDim.x) {
    const float4* p = reinterpret_cast<const float4*>(x + t * 8);
    float4 a = p[0], b = p[1];
    uint4 o4;
    o4.x = (unsigned)f2bf(a.x) | ((unsigned)f2bf(a.y) << 16);
    o4.y = (unsigned)f2bf(a.z) | ((unsigned)f2bf(a.w) << 16);
    o4.z = (unsigned)f2bf(b.x) | ((unsigned)f2bf(b.y) << 16);
    o4.w = (unsigned)f2bf(b.z) | ((unsigned)f2bf(b.w) << 16);
    *reinterpret_cast<uint4*>(xb + t * 8) = o4;
  }
}

// ---------------------------------------------------------------------------
// Kernel 3: 256x256-tile 8-phase GEMM (m201 template, plain HIP).
//   C[M][N] = A[M][K] @ Bm[N][K]^T + bias
//   8 waves (2M x 4N), per-wave 128x64 output = acc[8][4] f32x4.
//   LDS 128 KiB: 2 K-tile bufs x 4 half-tiles (B0,B1,A0,A1) x 16 KiB.
//   Half-tile layout: [kk=2][128 rows][32 elems], st_16x32 swizzle
//   (byte ^= ((byte>>9)&1)<<5) applied via pre-swizzled global source
//   (linear global_load_lds dest) + swizzled ds_read address.
//   Counted vmcnt(4) once per K-tile; never 0 in steady state.
// ---------------------------------------------------------------------------
__global__ __launch_bounds__(512, 2) void gemm256_kernel(
    const unsigned short* __restrict__ A,   // [MDIM][KDIM] bf16 bits
    const unsigned short* __restrict__ Bm,  // [NDIM][KDIM] bf16 bits (W')
    const float* __restrict__ bias,
    float* __restrict__ C) {
  __shared__ __align__(16) unsigned char lds[131072];

  const int tid  = threadIdx.x;
  const int wave = tid >> 6, lane = tid & 63;
  const int wm = wave >> 2, wn = wave & 3;       // 2 x 4 wave grid
  const int r16 = lane & 15, hi = lane >> 4;
  const int swz5 = ((r16 >> 3) & 1) << 5;        // read-side swizzle bit

  // XCD-aware bijective blockIdx swizzle (nwg = 1024, 1024 % 8 == 0)
  const int orig = blockIdx.x;
  const int bid  = (orig & 7) * 128 + (orig >> 3);
  const int bcol = (bid & 15) * 256;             // N-tile
  const int brow = (bid >> 4) * 256;             // M-tile

  // staging geometry: thread covers linear dest d = i*8192 + wave*1024 + lane*16
  //   -> logical (pre-swizzle-inverted) source row/col:
  const int st_row = wave * 16 + (lane >> 2);                    // 0..127
  const int st_col = ((lane & 3) * 8) ^ (((lane >> 5) & 1) << 4); // elem in [0,32)
  const unsigned short* Asrc = A  + (size_t)(brow + st_row) * KDIM + st_col;
  const unsigned short* Bsrc = Bm + (size_t)(bcol + st_row) * KDIM + st_col;
  unsigned char* const dwave = lds + wave * 1024;  // wave-uniform LDS base part

  // stage half-tile s (0=B0,1=B1,2=A0,3=A1) of K-tile tau: 2 gloads/wave
  auto stage = [&](int tau, int s) {
    const unsigned short* g = (s >= 2 ? Asrc + (size_t)(s - 2) * 128 * KDIM
                                      : Bsrc + (size_t)s * 128 * KDIM) + tau * BK;
    unsigned char* d = dwave + (tau & 1) * 65536 + s * 16384;
    gload_lds16(g,      d);            // kk-block 0
    gload_lds16(g + 32, d + 8192);     // kk-block 1
  };

  // read one MFMA fragment (16B) from a half-tile, swizzled
  auto ldfrag = [&](const unsigned char* half, int lrow, int kk) -> bf16x8 {
    return *reinterpret_cast<const bf16x8*>(
        half + kk * 8192 + lrow * 64 + (hi * 16 ^ swz5));
  };

  f32x4 acc[8][4];
#pragma unroll
  for (int m = 0; m < 8; ++m)
#pragma unroll
    for (int n = 0; n < 4; ++n) acc[m][n] = (f32x4){0.f, 0.f, 0.f, 0.f};

  // prologue: tile 0 fully + tile 1 B0,B1  (12 loads/wave), keep 4 in flight
#pragma unroll
  for (int h = 0; h < 6; ++h) stage(h >> 2, h & 3);
  asm volatile("s_waitcnt vmcnt(4)" ::: "memory");
  __builtin_amdgcn_s_barrier();

  bf16x8 a[4][2], bl[2][2], bh[2][2];

  for (int t = 0; t < NT; ++t) {
    const unsigned char* buf = lds + (t & 1) * 65536;
    const unsigned char* Ah = buf + (2 + wm) * 16384;
    const unsigned char* Bh = buf + (wn >> 1) * 16384;
    const int lrB = (wn & 1) * 64;

    // ---- P1: read A-lo + B-lo, stage A0(t+1), MFMA Q0 (m0-3 x n0-1)
#pragma unroll
    for (int m = 0; m < 4; ++m) {
      a[m][0] = ldfrag(Ah, m * 16 + r16, 0);
      a[m][1] = ldfrag(Ah, m * 16 + r16, 1);
    }
#pragma unroll
    for (int n = 0; n < 2; ++n) {
      bl[n][0] = ldfrag(Bh, lrB + n * 16 + r16, 0);
      bl[n][1] = ldfrag(Bh, lrB + n * 16 + r16, 1);
    }
    if (t + 1 < NT) stage(t + 1, 2);
    __builtin_amdgcn_s_barrier();
    asm volatile("s_waitcnt lgkmcnt(0)" ::: "memory");
    __builtin_amdgcn_s_setprio(1);
#pragma unroll
    for (int m = 0; m < 4; ++m)
#pragma unroll
      for (int n = 0; n < 2; ++n)
#pragma unroll
        for (int kk = 0; kk < 2; ++kk)
          acc[m][n] = __builtin_amdgcn_mfma_f32_16x16x32_bf16(
              a[m][kk], bl[n][kk], acc[m][n], 0, 0, 0);
    __builtin_amdgcn_s_setprio(0);
    __builtin_amdgcn_s_barrier();

    // ---- P2: read B-hi, stage A1(t+1), MFMA Q1 (m0-3 x n2-3)
#pragma unroll
    for (int n = 0; n < 2; ++n) {
      bh[n][0] = ldfrag(Bh, lrB + (n + 2) * 16 + r16, 0);
      bh[n][1] = ldfrag(Bh, lrB + (n + 2) * 16 + r16, 1);
    }
    if (t + 1 < NT) stage(t + 1, 3);
    __builtin_amdgcn_s_barrier();
    asm volatile("s_waitcnt lgkmcnt(0)" ::: "memory");
    __builtin_amdgcn_s_setprio(1);
#pragma unroll
    for (int m = 0; m < 4; ++m)
#pragma unroll
      for (int n = 0; n < 2; ++n)
#pragma unroll
        for (int kk = 0; kk < 2; ++kk)
          acc[m][n + 2] = __builtin_amdgcn_mfma_f32_16x16x32_bf16(
              a[m][kk], bh[n][kk], acc[m][n + 2], 0, 0, 0);
    __builtin_amdgcn_s_setprio(0);
    __builtin_amdgcn_s_barrier();

    // ---- P3: read A-hi, stage B0(t+2), MFMA Q2 (m4-7 x n2-3)
#pragma unroll
    for (int m = 0; m < 4; ++m) {
      a[m][0] = ldfrag(Ah, (m + 4) * 16 + r16, 0);
      a[m][1] = ldfrag(Ah, (m + 4) * 16 + r16, 1);
    }
    if (t + 2 < NT) stage(t + 2, 0);
    __builtin_amdgcn_s_barrier();
    asm volatile("s_waitcnt lgkmcnt(0)" ::: "memory");
    __builtin_amdgcn_s_setprio(1);
#pragma unroll
    for (int m = 0; m < 4; ++m)
#pragma unroll
      for (int n = 0; n < 2; ++n)
#pragma unroll
        for (int kk = 0; kk < 2; ++kk)
          acc[m + 4][n + 2] = __builtin_amdgcn_mfma_f32_16x16x32_bf16(
              a[m][kk], bh[n][kk], acc[m + 4][n + 2], 0, 0, 0);
    __builtin_amdgcn_s_setprio(0);
    __builtin_amdgcn_s_barrier();

    // ---- P4: stage B1(t+2), MFMA Q3 (m4-7 x n0-1), counted vmcnt wait
    if (t + 2 < NT) stage(t + 2, 1);
    __builtin_amdgcn_s_barrier();
    __builtin_amdgcn_s_setprio(1);
#pragma unroll
    for (int m = 0; m < 4; ++m)
#pragma unroll
      for (int n = 0; n < 2; ++n)
#pragma unroll
        for (int kk = 0; kk < 2; ++kk)
          acc[m + 4][n] = __builtin_amdgcn_mfma_f32_16x16x32_bf16(
              a[m][kk], bl[n][kk], acc[m + 4][n], 0, 0, 0);
    __builtin_amdgcn_s_setprio(0);
    if (t < NT - 2)       asm volatile("s_waitcnt vmcnt(4)" ::: "memory");
    else if (t == NT - 2) asm volatile("s_waitcnt vmcnt(0)" ::: "memory");
    __builtin_amdgcn_s_barrier();
  }

  // epilogue: C/D layout row=(lane>>4)*4+reg, col=lane&15 (verified m89/m91)
#pragma unroll
  for (int n = 0; n < 4; ++n) {
    const int col = bcol + wn * 64 + n * 16 + r16;
    const float bv = bias[col];
#pragma unroll
    for (int m = 0; m < 8; ++m) {
      const size_t row0 = (size_t)brow + wm * 128 + m * 16 + hi * 4;
#pragma unroll
      for (int j = 0; j < 4; ++j)
        C[(row0 + j) * NDIM + col] = acc[m][n][j] + bv;
    }
  }
}

// ---------------------------------------------------------------------------
extern "C" void kernel_launch(void* const* d_in, const int* in_sizes, int n_in,
                              void* d_out, int out_size, void* d_ws, size_t ws_size,
                              hipStream_t stream) {
  const float* x  = (const float*)d_in[0];   // [4,4096,4096]
  const float* W  = (const float*)d_in[1];   // [4096,4096]
  const float* b  = (const float*)d_in[2];   // [4096]
  const float* lA = (const float*)d_in[3];   // [16,4096]
  const float* lB = (const float*)d_in[4];   // [4096,16]
  float* out = (float*)d_out;                // [4,4096,4096] fp32

  unsigned short* xb = (unsigned short*)d_ws;
  unsigned short* Wp = (unsigned short*)((char*)d_ws + (size_t)MDIM * KDIM * 2);

  conv_x_kernel<<<2048, 256, 0, stream>>>(x, xb);
  prep_w_kernel<<<2048, 256, 0, stream>>>(W, lA, lB, Wp);

  gemm256_kernel<<<1024, 512, 0, stream>>>(xb, Wp, b, out);
}